// Round 6
// baseline (125.208 us; speedup 1.0000x reference)
//
#include <hip/hip_runtime.h>
#include <stdint.h>

typedef __attribute__((ext_vector_type(8))) short short8;
typedef __attribute__((ext_vector_type(4))) float f32x4;
typedef unsigned short ushort_t;

// fp32 -> bf16 round-to-nearest-even
__device__ __forceinline__ ushort_t f2bf(float f) {
  uint32_t u = __float_as_uint(f);
  u += 0x7fffu + ((u >> 16) & 1u);
  return (ushort_t)(u >> 16);
}

__device__ __forceinline__ uint2 pack4(float4 v) {
  return make_uint2((uint32_t)f2bf(v.x) | ((uint32_t)f2bf(v.y) << 16),
                    (uint32_t)f2bf(v.z) | ((uint32_t)f2bf(v.w) << 16));
}

// async global->LDS, 16B per lane; LDS dest = wave-uniform base + lane*16
__device__ __forceinline__ void load_lds16(const ushort_t* g, ushort_t* l) {
  __builtin_amdgcn_global_load_lds(
      (const __attribute__((address_space(1))) uint32_t*)g,
      (__attribute__((address_space(3))) uint32_t*)l, 16, 0, 0);
}

// --- K1: two independent jobs in one dispatch (1024 blocks) -----------------
// blocks 512..1023: A-prep — rowsum(A+I) -> dis, dis*mask; (A+I) -> Abf bf16
// blocks 0..511   : HLt[b][o][m] = sum_i W[o,i]*H[b,m,i] + bias[o]  (bf16)
__global__ __launch_bounds__(256) void k_phase1(
    const float* __restrict__ W,     // [256][256] fp32
    const float* __restrict__ H,     // [32][512][256] fp32
    const float* __restrict__ bias,  // [256]
    const float* __restrict__ mask,  // [32*512]
    const float* __restrict__ A,     // [32][512][512] fp32
    ushort_t* __restrict__ Abf,      // [32][512][512] bf16 out
    float* __restrict__ dis,         // [32*512] out
    float* __restrict__ dmask,       // [32*512] out
    ushort_t* __restrict__ HLt) {    // [32][256][512] bf16 out (unscaled)
  __shared__ ushort_t smem[12288];  // 24 KB (GEMM job only)
  const int bid = blockIdx.x;
  const int tid = threadIdx.x, lane = tid & 63, wv = tid >> 6;

  if (bid >= 512) {  // ---------------- A-prep: 32 rows per block ------------
    const float4* A4 = (const float4*)A;
    const int row0 = (bid - 512) * 32 + wv * 8;
#pragma unroll
    for (int i = 0; i < 8; ++i) {
      const int row = row0 + i;
      const int n = row & 511;
      const float4* src = A4 + (size_t)row * 128;
      uint2* dst = (uint2*)(Abf + (size_t)row * 512);
      float s = 0.0f;
#pragma unroll
      for (int j = 0; j < 2; ++j) {
        const int idx = j * 64 + lane;
        float4 v = src[idx];
        const int c0 = idx * 4;
        v.x += (float)(c0 == n);  // identity fold (included in rowsum)
        v.y += (float)(c0 + 1 == n);
        v.z += (float)(c0 + 2 == n);
        v.w += (float)(c0 + 3 == n);
        s += (v.x + v.y) + (v.z + v.w);
        dst[idx] = pack4(v);
      }
#pragma unroll
      for (int off = 32; off > 0; off >>= 1) s += __shfl_xor(s, off, 64);
      if (lane == 0) {
        float d = rsqrtf(s + 1e-8f);
        dis[row] = d;
        dmask[row] = d * mask[row];
      }
    }
    return;
  }

  // ------------- HL GEMM: tile 64(o) x 128(m), K=256, BK=32 -----------------
  ushort_t* As1 = smem;         // [2][64*32]
  ushort_t* Bs1 = smem + 4096;  // [2][128*32]
  const int yo = bid >> 7, rr = bid & 127;
  const int batch = rr >> 2, xm = rr & 3;
  const int ot0 = yo * 64, mt0 = xm * 128;
  const int wo = wv & 1, wmh = wv >> 1;
  const int lr = lane & 15, q = lane >> 4;
  const float* Hb = H + (size_t)batch * 512 * 256;
  const int a_r = tid >> 2, a_kc = (tid & 3) * 8;
  const int b_r = tid >> 1, b_kc = (tid & 1) * 16;

  f32x4 acc[2][4];
#pragma unroll
  for (int i = 0; i < 2; ++i)
#pragma unroll
    for (int j = 0; j < 4; ++j) acc[i][j] = {0.f, 0.f, 0.f, 0.f};

  float4 ra[2], rb[4];
  auto gload = [&](int k0) {
    const float* wp = W + (size_t)(ot0 + a_r) * 256 + k0 + a_kc;
    ra[0] = *(const float4*)wp;
    ra[1] = *(const float4*)(wp + 4);
    const float* hp = Hb + (size_t)(mt0 + b_r) * 256 + k0 + b_kc;
#pragma unroll
    for (int j = 0; j < 4; ++j) rb[j] = *(const float4*)(hp + 4 * j);
  };
  auto stash = [&](int p) {
    uint2 a0 = pack4(ra[0]), a1 = pack4(ra[1]);
    *(uint4*)&As1[p * 2048 + a_r * 32 + a_kc] =
        make_uint4(a0.x, a0.y, a1.x, a1.y);
    uint2 b0 = pack4(rb[0]), b1 = pack4(rb[1]);
    uint2 b2 = pack4(rb[2]), b3 = pack4(rb[3]);
    *(uint4*)&Bs1[p * 4096 + b_r * 32 + b_kc] =
        make_uint4(b0.x, b0.y, b1.x, b1.y);
    *(uint4*)&Bs1[p * 4096 + b_r * 32 + b_kc + 8] =
        make_uint4(b2.x, b2.y, b3.x, b3.y);
  };
  auto compute = [&](int p) {
    short8 af[2], bfr[4];
#pragma unroll
    for (int mt = 0; mt < 2; ++mt)
      af[mt] =
          *(const short8*)&As1[p * 2048 + (wo * 32 + mt * 16 + lr) * 32 + q * 8];
#pragma unroll
    for (int nt = 0; nt < 4; ++nt)
      bfr[nt] = *(const short8*)&Bs1[p * 4096 +
                                     (wmh * 64 + nt * 16 + lr) * 32 + q * 8];
#pragma unroll
    for (int mt = 0; mt < 2; ++mt)
#pragma unroll
      for (int nt = 0; nt < 4; ++nt)
        acc[mt][nt] = __builtin_amdgcn_mfma_f32_16x16x32_bf16(
            af[mt], bfr[nt], acc[mt][nt], 0, 0, 0);
  };

  gload(0);
#pragma unroll
  for (int it = 0; it < 8; ++it) {
    stash(it & 1);
    __syncthreads();
    if (it + 1 < 8) gload((it + 1) * 32);
    compute(it & 1);
  }

#pragma unroll
  for (int mt = 0; mt < 2; ++mt) {
    const int ob = ot0 + wo * 32 + mt * 16 + q * 4;
    float bs[4];
#pragma unroll
    for (int r = 0; r < 4; ++r) bs[r] = bias[ob + r];
#pragma unroll
    for (int nt = 0; nt < 4; ++nt) {
      const int m = mt0 + wmh * 64 + nt * 16 + lr;
      ushort_t* dstp = HLt + ((size_t)batch * 256 + ob) * 512 + m;
#pragma unroll
      for (int r = 0; r < 4; ++r)
        dstp[(size_t)r * 512] = f2bf(acc[mt][nt][r] + bs[r]);
    }
  }
}

// --- K2: in-place Gt[b][o][m] *= dis[b,m]  (8 bf16 per thread) --------------
__global__ __launch_bounds__(256) void k_scale(ushort_t* __restrict__ G,
                                               const float* __restrict__ dis) {
  const int idx = blockIdx.x * 256 + threadIdx.x;  // uint4 index
  const size_t e0 = (size_t)idx * 8;
  const int b = (int)(e0 >> 17);  // 256*512 elems per batch
  const int m = (int)(e0 & 511);
  const float* dp = dis + (b << 9) + m;
  float4 d0 = *(const float4*)dp;
  float4 d1 = *(const float4*)(dp + 4);
  uint4 v = ((const uint4*)G)[idx];
  auto sc2 = [](uint32_t p, float da, float db) -> uint32_t {
    float lo = __uint_as_float((p & 0xffffu) << 16) * da;
    float hi = __uint_as_float(p & 0xffff0000u) * db;
    return (uint32_t)f2bf(lo) | ((uint32_t)f2bf(hi) << 16);
  };
  v.x = sc2(v.x, d0.x, d0.y);
  v.y = sc2(v.y, d0.z, d0.w);
  v.z = sc2(v.z, d1.x, d1.y);
  v.w = sc2(v.w, d1.z, d1.w);
  ((uint4*)G)[idx] = v;
}

// --- K3: out[b][n][o] = relu( dmask[n] * sum_m Abf[n,m]*Gt[o,m] ) -----------
// tile 64(n) x 128(o), K=512, BK=64 as 2x32-wide slabs (conflict-free LDS
// layout preserved); both operands via global_load_lds; 8 barriers total.
// bid = yo*256 + batch*8 + xn  (the 2 o-blocks sharing Abf rows -> same XCD)
__global__ __launch_bounds__(256) void k_out(
    const ushort_t* __restrict__ Abf,  // [32][512][512] bf16 (A+I)
    const ushort_t* __restrict__ Gt,   // [32][256][512] bf16 (dis-scaled)
    const float* __restrict__ dmask,   // [32*512]
    float* __restrict__ out) {         // [32][512][256] fp32
  __shared__ ushort_t As[4][64 * 32];   // slots: pair(0,1) / pair(2,3)
  __shared__ ushort_t Bs[4][128 * 32];
  const int bid = blockIdx.x;
  const int yo = bid >> 8, rem = bid & 255;
  const int batch = rem >> 3, xn = rem & 7;
  const int nt0 = xn * 64, ot0 = yo * 128;
  const int tid = threadIdx.x, lane = tid & 63, wv = tid >> 6;
  const int wn2 = wv & 1;   // n half (2 x 32)
  const int wo2 = wv >> 1;  // o half (2 x 64)
  const int lr = lane & 15, q = lane >> 4;
  const int rstage = lane >> 2, koff = (lane & 3) * 8;
  const ushort_t* Ab = Abf + (size_t)batch * 512 * 512;
  const ushort_t* Gb = Gt + (size_t)batch * 256 * 512;

  f32x4 acc[2][4];
#pragma unroll
  for (int i = 0; i < 2; ++i)
#pragma unroll
    for (int j = 0; j < 4; ++j) acc[i][j] = {0.f, 0.f, 0.f, 0.f};

  auto stage = [&](int k0, int slot) {  // one 32-wide slab
    load_lds16(Ab + (size_t)(nt0 + wv * 16 + rstage) * 512 + k0 + koff,
               &As[slot][wv * 512]);
#pragma unroll
    for (int j = 0; j < 2; ++j) {
      const int c = wv * 2 + j;
      load_lds16(Gb + (size_t)(ot0 + c * 16 + rstage) * 512 + k0 + koff,
                 &Bs[slot][c * 512]);
    }
  };
  auto compute = [&](int slot) {
    short8 af[2], bfr[4];
#pragma unroll
    for (int mt = 0; mt < 2; ++mt)
      af[mt] =
          *(const short8*)&As[slot][(wn2 * 32 + mt * 16 + lr) * 32 + q * 8];
#pragma unroll
    for (int nt = 0; nt < 4; ++nt)
      bfr[nt] =
          *(const short8*)&Bs[slot][(wo2 * 64 + nt * 16 + lr) * 32 + q * 8];
#pragma unroll
    for (int mt = 0; mt < 2; ++mt)
#pragma unroll
      for (int nt = 0; nt < 4; ++nt)
        acc[mt][nt] = __builtin_amdgcn_mfma_f32_16x16x32_bf16(
            af[mt], bfr[nt], acc[mt][nt], 0, 0, 0);
  };

  stage(0, 0);
  stage(32, 1);
#pragma unroll
  for (int it = 0; it < 8; ++it) {  // BK=64 per iteration
    __syncthreads();
    if (it + 1 < 8) {
      const int base = ((it + 1) & 1) * 2, k0 = (it + 1) * 64;
      stage(k0, base);
      stage(k0 + 32, base + 1);
    }
    const int cb = (it & 1) * 2;
    compute(cb);
    compute(cb + 1);
  }

#pragma unroll
  for (int mt = 0; mt < 2; ++mt) {
    const int nb = nt0 + wn2 * 32 + mt * 16 + q * 4;
    float sc[4];
#pragma unroll
    for (int r = 0; r < 4; ++r) sc[r] = dmask[batch * 512 + nb + r];
#pragma unroll
    for (int nt = 0; nt < 4; ++nt) {
      const int o = ot0 + wo2 * 64 + nt * 16 + lr;
      float* dstp = out + ((size_t)(batch * 512 + nb)) * 256 + o;
#pragma unroll
      for (int r = 0; r < 4; ++r) {
        float v = acc[mt][nt][r] * sc[r];
        dstp[(size_t)r * 256] = v > 0.0f ? v : 0.0f;
      }
    }
  }
}

extern "C" void kernel_launch(void* const* d_in, const int* in_sizes, int n_in,
                              void* d_out, int out_size, void* d_ws,
                              size_t ws_size, hipStream_t stream) {
  const float* H = (const float*)d_in[0];     // [32][512][256]
  const float* A = (const float*)d_in[1];     // [32][512][512]
  const float* mask = (const float*)d_in[2];  // [32][512]
  const float* W = (const float*)d_in[3];     // [256][256]
  const float* b = (const float*)d_in[4];     // [256]
  float* out = (float*)d_out;                 // [32][512][256]

  char* ws = (char*)d_ws;
  ushort_t* Abf = (ushort_t*)ws;                        // 16 MiB
  ushort_t* Gt = (ushort_t*)(ws + 16777216);            // 8 MiB
  float* dis = (float*)(ws + 16777216 + 8388608);       // 64 KiB
  float* dmask = (float*)(ws + 16777216 + 8388608 + 65536);

  // 1) concurrent: [A-prep -> Abf, dis, dmask] || [HLt = W@H^T + b]
  k_phase1<<<1024, 256, 0, stream>>>(W, H, b, mask, A, Abf, dis, dmask, Gt);
  // 2) Gt *= dis[m]  (in-place)
  k_scale<<<2048, 256, 0, stream>>>(Gt, dis);
  // 3) out = relu(dmask[n] * Abf @ Gt^T)
  k_out<<<512, 256, 0, stream>>>(Abf, Gt, dmask, out);
}